// Round 2
// baseline (303.734 us; speedup 1.0000x reference)
//
#include <hip/hip_runtime.h>
#include <cmath>

#define HH 1024
#define WW 1024
#define KS 51
#define RAD 25
#define PLANE (HH * WW)

struct GaussW { float w[KS]; };

// ---------------------------------------------------------------------------
// Horizontal 51-tap blur — NO LDS (R1 had 16-way bank conflicts = 72% of
// cycles). Each thread: 8 consecutive outputs, 64-float register window
// loaded via 16 aligned global float4 loads (lane windows overlap; L1/L2
// serve the 2x refetch). Weights arrive by value -> SGPRs -> v_fmac s,v.
// Block = 2 rows x 128 threads.
// ---------------------------------------------------------------------------
__global__ __launch_bounds__(256) void hblur_kernel(const float* __restrict__ x,
                                                    float* __restrict__ tmp,
                                                    GaussW gw)
{
    const int t   = threadIdx.x;
    const int r   = t >> 7;
    const int tid = t & 127;
    const long long row = (long long)blockIdx.x * 2 + r;
    const float* src = x + row * WW;

    const int j0 = tid * 8;            // first output col; j0-28 is 16B aligned

    // window covers cols j0-28 .. j0+35 (need j0-25 .. j0+32)
    float win[64];
    #pragma unroll
    for (int i = 0; i < 16; i++) {
        const int b = j0 - 28 + i * 4;             // compile-time per i
        if (b >= 0 && b + 3 < WW) {                // interior: aligned float4
            *(float4*)(&win[i * 4]) = *(const float4*)(src + b);
        } else {                                    // only first/last 4 threads
            #pragma unroll
            for (int q = 0; q < 4; q++) {
                const int c = b + q;
                win[i * 4 + q] = (c >= 0 && c < WW) ? src[c] : 0.f;
            }
        }
    }

    float acc[8];
    #pragma unroll
    for (int d = 0; d < 8; d++) acc[d] = 0.f;
    #pragma unroll
    for (int k = 0; k < KS; k++) {
        const float wk = gw.w[k];                  // SGPR
        #pragma unroll
        for (int d = 0; d < 8; d++)
            acc[d] = fmaf(wk, win[d + k + 3], acc[d]);   // col j0+d-25+k
    }

    float* dst = tmp + row * WW;
    *(float4*)(dst + j0)     = make_float4(acc[0], acc[1], acc[2], acc[3]);
    *(float4*)(dst + j0 + 4) = make_float4(acc[4], acc[5], acc[6], acc[7]);
}

// ---------------------------------------------------------------------------
// Vertical 51-tap blur + screen blend + clamp, float4-per-lane.
// Block = 256 cols x 64 rows tile; thread = 4 consecutive cols x 16 rows.
// 66 coalesced float4 loads (1KB/instr per wave) feed 64 accumulators,
// input-stationary. Row guards are wave-uniform. tile_y is the inner dispatch
// coordinate so vertically-adjacent blocks share halo rows in L2.
// ---------------------------------------------------------------------------
__global__ __launch_bounds__(256) void vblend_kernel(const float* __restrict__ tmp,
                                                     const float* __restrict__ x,
                                                     float* __restrict__ out,
                                                     GaussW gw,
                                                     const float* __restrict__ amountp)
{
    const int t      = threadIdx.x;
    const int bid    = blockIdx.x;
    const int plane  = bid >> 6;            // 64 tiles per plane
    const int rem    = bid & 63;
    const int tile_x = rem >> 4;            // 4 col-tiles of 256
    const int tile_y = rem & 15;            // inner -> vertical L2 reuse
    const int c0     = tile_x * 256 + (t & 63) * 4;
    const int r0     = tile_y * 64 + (t >> 6) * 16;   // wave-uniform row group

    const float* tp = tmp + (size_t)plane * PLANE + c0;

    float4 acc[16];
    #pragma unroll
    for (int j = 0; j < 16; j++) acc[j] = make_float4(0.f, 0.f, 0.f, 0.f);

    #pragma unroll
    for (int i = 0; i < 66; i++) {
        const int ri = r0 - RAD + i;
        float4 v = make_float4(0.f, 0.f, 0.f, 0.f);
        if (ri >= 0 && ri < HH) v = *(const float4*)(tp + (size_t)ri * WW);
        #pragma unroll
        for (int j = 0; j < 16; j++) {
            const int k = i - j;                  // compile-time tap index
            if (k >= 0 && k < KS) {
                const float wk = gw.w[k];
                acc[j].x = fmaf(wk, v.x, acc[j].x);
                acc[j].y = fmaf(wk, v.y, acc[j].y);
                acc[j].z = fmaf(wk, v.z, acc[j].z);
                acc[j].w = fmaf(wk, v.w, acc[j].w);
            }
        }
    }

    const float p = amountp[0];
    const float s = 1.2f * (0.4f / (1.f + expf(-p)));   // 1.2 * amount

    const float* xp = x   + (size_t)plane * PLANE + c0;
    float*       op = out + (size_t)plane * PLANE + c0;
    #pragma unroll
    for (int j = 0; j < 16; j++) {
        const float4 xv = *(const float4*)(xp + (size_t)(r0 + j) * WW);
        float4 res;
        res.x = 1.f - (1.f - xv.x) * (1.f - s * acc[j].x);
        res.y = 1.f - (1.f - xv.y) * (1.f - s * acc[j].y);
        res.z = 1.f - (1.f - xv.z) * (1.f - s * acc[j].z);
        res.w = 1.f - (1.f - xv.w) * (1.f - s * acc[j].w);
        res.x = fminf(fmaxf(res.x, 0.f), 1.f);
        res.y = fminf(fmaxf(res.y, 0.f), 1.f);
        res.z = fminf(fmaxf(res.z, 0.f), 1.f);
        res.w = fminf(fmaxf(res.w, 0.f), 1.f);
        *(float4*)(op + (size_t)(r0 + j) * WW) = res;
    }
}

// ---------------------------------------------------------------------------
extern "C" void kernel_launch(void* const* d_in, const int* in_sizes, int n_in,
                              void* d_out, int out_size, void* d_ws, size_t ws_size,
                              hipStream_t stream)
{
    const float* x       = (const float*)d_in[0];
    const float* amountp = (const float*)d_in[1];
    float* out = (float*)d_out;
    float* tmp = (float*)d_ws;

    // Gaussian weights (sigma=15, size 51), normalized — identical every call.
    GaussW gw;
    {
        double e[KS], sum = 0.0;
        for (int i = 0; i < KS; i++) {
            const double d = (double)(i - RAD);
            e[i] = exp(-d * d / (2.0 * 15.0 * 15.0));
            sum += e[i];
        }
        for (int i = 0; i < KS; i++) gw.w[i] = (float)(e[i] / sum);
    }

    const int total_planes = in_sizes[0] / PLANE;      // 24
    const size_t plane_bytes = (size_t)PLANE * sizeof(float);
    int P = (int)(ws_size / plane_bytes);
    if (P < 1) P = 1;
    if (P > total_planes) P = total_planes;

    for (int p0 = 0; p0 < total_planes; p0 += P) {
        const int pc = (total_planes - p0 < P) ? (total_planes - p0) : P;
        hblur_kernel<<<pc * 512, 256, 0, stream>>>(x + (size_t)p0 * PLANE, tmp, gw);
        vblend_kernel<<<pc * 64, 256, 0, stream>>>(tmp,
                                                   x + (size_t)p0 * PLANE,
                                                   out + (size_t)p0 * PLANE,
                                                   gw, amountp);
    }
}

// Round 3
// 295.444 us; speedup vs baseline: 1.0281x; 1.0281x over previous
//
#include <hip/hip_runtime.h>
#include <cmath>

#define HH 1024
#define WW 1024
#define KS 51
#define RAD 25
#define PLANE (HH * WW)

struct GaussW { float w[KS]; };

// ---------------------------------------------------------------------------
// Horizontal 51-tap blur. Thread = 16 consecutive outputs; 18 float4 global
// loads feed 816 FMAs, input-stationary: each loaded float4 is consumed
// immediately (acc[16] + v live -> low VGPR -> high occupancy + load ILP).
// Weights by value -> SGPRs -> v_fmac s,v. Block = 4 rows x 64 threads;
// wave == one row so edge divergence stays in 2 lanes.
// ---------------------------------------------------------------------------
__global__ __launch_bounds__(256) void hblur_kernel(const float* __restrict__ x,
                                                    float* __restrict__ tmp,
                                                    GaussW gw)
{
    const int t    = threadIdx.x;
    const int lane = t & 63;
    const int r    = t >> 6;                       // wave-uniform
    const long long row = (long long)blockIdx.x * 4 + r;
    const float* src = x + row * WW;
    const int j0 = lane * 16;                      // outputs j0..j0+15

    float acc[16];
    #pragma unroll
    for (int d = 0; d < 16; d++) acc[d] = 0.f;

    // window covers cols j0-28 .. j0+43 (need j0-25 .. j0+40); 18 aligned float4
    #pragma unroll
    for (int i = 0; i < 18; i++) {
        const int b = j0 - 28 + i * 4;
        float4 v;
        if (b >= 0 && b + 3 < WW) {
            v = *(const float4*)(src + b);
        } else {                                   // only lane 0 / lane 63
            float tv[4];
            #pragma unroll
            for (int q = 0; q < 4; q++) {
                const int c = b + q;
                tv[q] = (c >= 0 && c < WW) ? src[c] : 0.f;
            }
            v = make_float4(tv[0], tv[1], tv[2], tv[3]);
        }
        const float vq[4] = {v.x, v.y, v.z, v.w};
        #pragma unroll
        for (int q = 0; q < 4; q++) {
            const int wi = i * 4 + q;              // window index: col j0-28+wi
            #pragma unroll
            for (int d = 0; d < 16; d++) {
                const int k = wi - 3 - d;          // compile-time tap index
                if (k >= 0 && k < KS)
                    acc[d] = fmaf(gw.w[k], vq[q], acc[d]);
            }
        }
    }

    float* dst = tmp + row * WW;
    #pragma unroll
    for (int g = 0; g < 4; g++)
        *(float4*)(dst + j0 + g * 4) =
            make_float4(acc[g*4], acc[g*4+1], acc[g*4+2], acc[g*4+3]);
}

// ---------------------------------------------------------------------------
// Vertical 51-tap blur + screen blend + clamp. Thread = 2 consecutive cols
// (float2) x 16 rows: acc = 32 VGPRs (R2's float4 x 16 was ~VGPR-bound and
// regressed). 66 coalesced float2 loads (512 B/instr) -> 1632 FMAs,
// input-stationary. Row guards wave-uniform. tile_y inner so vertically-
// adjacent blocks share halo rows in L2.
// ---------------------------------------------------------------------------
__global__ __launch_bounds__(256) void vblend_kernel(const float* __restrict__ tmp,
                                                     const float* __restrict__ x,
                                                     float* __restrict__ out,
                                                     GaussW gw,
                                                     const float* __restrict__ amountp)
{
    const int t      = threadIdx.x;
    const int bid    = blockIdx.x;
    const int plane  = bid >> 7;            // 128 tiles per plane
    const int rem    = bid & 127;
    const int tile_x = rem >> 4;            // 8 col-tiles of 128
    const int tile_y = rem & 15;            // inner -> vertical L2 reuse
    const int c0     = tile_x * 128 + (t & 63) * 2;
    const int r0     = tile_y * 64 + (t >> 6) * 16;   // wave-uniform row group

    const float* tp = tmp + (size_t)plane * PLANE + c0;

    float2 acc[16];
    #pragma unroll
    for (int j = 0; j < 16; j++) acc[j] = make_float2(0.f, 0.f);

    #pragma unroll
    for (int i = 0; i < 66; i++) {
        const int ri = r0 - RAD + i;
        float2 v = make_float2(0.f, 0.f);
        if (ri >= 0 && ri < HH) v = *(const float2*)(tp + (size_t)ri * WW);
        #pragma unroll
        for (int j = 0; j < 16; j++) {
            const int k = i - j;                  // compile-time tap index
            if (k >= 0 && k < KS) {
                const float wk = gw.w[k];
                acc[j].x = fmaf(wk, v.x, acc[j].x);
                acc[j].y = fmaf(wk, v.y, acc[j].y);
            }
        }
    }

    const float p = amountp[0];
    const float s = 1.2f * (0.4f / (1.f + expf(-p)));   // 1.2 * amount

    const float* xp = x   + (size_t)plane * PLANE + c0;
    float*       op = out + (size_t)plane * PLANE + c0;
    #pragma unroll
    for (int j = 0; j < 16; j++) {
        const float2 xv = *(const float2*)(xp + (size_t)(r0 + j) * WW);
        float2 res;
        res.x = 1.f - (1.f - xv.x) * (1.f - s * acc[j].x);
        res.y = 1.f - (1.f - xv.y) * (1.f - s * acc[j].y);
        res.x = fminf(fmaxf(res.x, 0.f), 1.f);
        res.y = fminf(fmaxf(res.y, 0.f), 1.f);
        *(float2*)(op + (size_t)(r0 + j) * WW) = res;
    }
}

// ---------------------------------------------------------------------------
extern "C" void kernel_launch(void* const* d_in, const int* in_sizes, int n_in,
                              void* d_out, int out_size, void* d_ws, size_t ws_size,
                              hipStream_t stream)
{
    const float* x       = (const float*)d_in[0];
    const float* amountp = (const float*)d_in[1];
    float* out = (float*)d_out;
    float* tmp = (float*)d_ws;

    // Gaussian weights (sigma=15, size 51), normalized — identical every call.
    GaussW gw;
    {
        double e[KS], sum = 0.0;
        for (int i = 0; i < KS; i++) {
            const double d = (double)(i - RAD);
            e[i] = exp(-d * d / (2.0 * 15.0 * 15.0));
            sum += e[i];
        }
        for (int i = 0; i < KS; i++) gw.w[i] = (float)(e[i] / sum);
    }

    const int total_planes = in_sizes[0] / PLANE;      // 24
    const size_t plane_bytes = (size_t)PLANE * sizeof(float);
    int P = (int)(ws_size / plane_bytes);
    if (P < 1) P = 1;
    if (P > total_planes) P = total_planes;

    for (int p0 = 0; p0 < total_planes; p0 += P) {
        const int pc = (total_planes - p0 < P) ? (total_planes - p0) : P;
        hblur_kernel<<<pc * 256, 256, 0, stream>>>(x + (size_t)p0 * PLANE, tmp, gw);
        vblend_kernel<<<pc * 128, 256, 0, stream>>>(tmp,
                                                    x + (size_t)p0 * PLANE,
                                                    out + (size_t)p0 * PLANE,
                                                    gw, amountp);
    }
}